// Round 6
// baseline (52.741 us; speedup 1.0000x reference)
//
#include <hip/hip_runtime.h>
#include <hip/hip_bf16.h>
#include <math.h>

#define KC 32
#define DC 128
#define QC 16
#define NPTS 20000

// ws layout (bytes):
//   C2p[32] f32      @ 0
//   BT_HI[544*128] s @ 128
//   BT_LO[544*128] s @ 139392
//   XH[20000*128] s  @ 278656
//   XL[20000*128] s  @ 5398656
//   S2H[20000] f32   @ 10518656   (pre-scaled by 0.5)
#define WS_C2P_B 0
#define WS_BTH_B 128
#define WS_BTL_B 139392
#define WS_XH_B  278656
#define WS_XL_B  5398656
#define WS_S2_B  10518656

typedef __attribute__((ext_vector_type(8)))  short bf16x8;
typedef __attribute__((ext_vector_type(4)))  float f32x4;
typedef __attribute__((ext_vector_type(16))) float f32x16;

// round-to-nearest-even bf16 split
static __device__ __forceinline__ short f2bf(float x) {
    union { float f; unsigned u; } v; v.f = x;
    unsigned r = v.u + 0x7fffu + ((v.u >> 16) & 1u);
    return (short)(r >> 16);
}
static __device__ __forceinline__ float bf2f(short h) {
    union { unsigned u; float f; } v; v.u = ((unsigned)(unsigned short)h) << 16;
    return v.f;
}

// ---------------------------------------------------------------------------
// Kernel 1 (fused prep): blocks 0..31 per-component Woodbury precompute
// (G rows scaled by 1/sqrt(2), w' row, C2'); blocks 32..345 convert 64 X rows
// each to bf16 hi/lo and store 0.5 * x^T Psi'^-1 x.
// ---------------------------------------------------------------------------
__global__ __launch_bounds__(256) void mfa_prep(
    const float* __restrict__ X, const float* __restrict__ log_pi,
    const float* __restrict__ mu, const float* __restrict__ Lam,
    const float* __restrict__ log_psi,
    float* __restrict__ c2p, short* __restrict__ btH, short* __restrict__ btL,
    short* __restrict__ xH, short* __restrict__ xL, float* __restrict__ s2g)
{
    int t = threadIdx.x;
    if (blockIdx.x >= KC) {
        // ---- conversion path: 64 rows per block ----
        int xb = blockIdx.x - KC;          // 0..313
        int cseg = t & 15, rloc = t >> 4;
        int c0 = cseg * 8;
        float is[8];
#pragma unroll
        for (int j = 0; j < 8; j++) {
            float psi = expf(log_psi[c0 + j]) + 1e-5f + 1e-4f;
            is[j] = 1.0f / psi;
        }
#pragma unroll
        for (int p = 0; p < 4; p++) {
            int r = xb*64 + p*16 + rloc;
            if (r < NPTS) {
                float xs[8];
                const float* xp = X + (size_t)r*DC + c0;
                *(float4*)&xs[0] = *(const float4*)xp;
                *(float4*)&xs[4] = *(const float4*)(xp + 4);
                bf16x8 hv, lv;
                float s2 = 0.f;
#pragma unroll
                for (int j = 0; j < 8; j++) {
                    short hi = f2bf(xs[j]);
                    float hf = bf2f(hi);
                    hv[j] = hi;
                    lv[j] = f2bf(xs[j] - hf);
                    s2 = fmaf(xs[j]*is[j], xs[j], s2);
                }
                *(bf16x8*)(xH + (size_t)r*DC + c0) = hv;
                *(bf16x8*)(xL + (size_t)r*DC + c0) = lv;
                s2 += __shfl_xor(s2, 1, 16);
                s2 += __shfl_xor(s2, 2, 16);
                s2 += __shfl_xor(s2, 4, 16);
                s2 += __shfl_xor(s2, 8, 16);
                if (cseg == 0) s2g[r] = 0.5f * s2;
            }
        }
        return;
    }
    // ---- per-component path ----
    int k = blockIdx.x;
    __shared__ float invpsiS[DC], muS[DC];
    __shared__ float lamR[DC*17];        // Lam[d][q]
    __shared__ float lamSc[DC*17];       // Lam[d][q]*invpsi[d]
    __shared__ float MS[QC*QC], LSm[QC*QC];
    __shared__ float invDS[QC];
    __shared__ float GT[QC*129];
    __shared__ float hS[QC];
    __shared__ float redS[4];
    __shared__ float hhS, ldS;

    float lp = 0.f, ipm = 0.f;
    if (t < DC) {
        float psi = expf(log_psi[t]) + 1e-5f + 1e-4f;
        float ip = 1.0f / psi;
        invpsiS[t] = ip;
        lp = logf(psi);
        float m = mu[k*DC + t];
        muS[t] = m;
        ipm = ip*m*m;
    }
    __syncthreads();
    for (int e = t; e < DC*QC; e += 256) {
        int d = e >> 4, q = e & 15;
        float lv = Lam[k*DC*QC + e];
        lamR[d*17 + q]  = lv;
        lamSc[d*17 + q] = lv * invpsiS[d];
    }
    __syncthreads();
    {   // M = I + Lam^T diag(invpsi) Lam
        int q = t >> 4, r = t & 15;
        float s0 = (q == r) ? 1.0f : 0.0f, s1 = 0.f, s2 = 0.f, s3 = 0.f;
#pragma unroll 1
        for (int d = 0; d < DC; d += 4) {
            s0 = fmaf(lamSc[(d+0)*17 + q], lamR[(d+0)*17 + r], s0);
            s1 = fmaf(lamSc[(d+1)*17 + q], lamR[(d+1)*17 + r], s1);
            s2 = fmaf(lamSc[(d+2)*17 + q], lamR[(d+2)*17 + r], s2);
            s3 = fmaf(lamSc[(d+3)*17 + q], lamR[(d+3)*17 + r], s3);
        }
        MS[q*QC + r] = (s0 + s1) + (s2 + s3);
    }
    __syncthreads();
    if (t < QC) {       // 16-lane shuffle Cholesky; lane i owns row i
        float m[QC], lrow[QC];
#pragma unroll
        for (int j = 0; j < QC; j++) m[j] = MS[t*QC + j];
#pragma unroll
        for (int j = 0; j < QC; j++) {
            float piv = __shfl(m[j], j, 16);
            float ljj = sqrtf(piv);
            float lij = m[j] / ljj;
            lrow[j] = lij;
#pragma unroll
            for (int r = j + 1; r < QC; r++)
                m[r] = fmaf(-lij, __shfl(lij, r, 16), m[r]);
        }
#pragma unroll
        for (int j = 0; j < QC; j++) LSm[t*QC + j] = lrow[j];
        invDS[t] = 1.0f / lrow[t];
        float ld = 2.0f * logf(lrow[t]);
        ld += __shfl_xor(ld, 1, 16);
        ld += __shfl_xor(ld, 2, 16);
        ld += __shfl_xor(ld, 4, 16);
        ld += __shfl_xor(ld, 8, 16);
        if (t == 0) ldS = ld;
    }
    __syncthreads();
    float g[QC];
    if (t < DC) {       // forward solve: column t of G
        float b[QC];
#pragma unroll
        for (int q = 0; q < QC; q++) b[q] = lamSc[t*17 + q];
#pragma unroll
        for (int i = 0; i < QC; i++) {
            float s = b[i];
#pragma unroll
            for (int x = 0; x < i; x++)
                s = fmaf(-LSm[i*QC + x], g[x], s);
            g[i] = s * invDS[i];
        }
        const float is2 = 0.70710678118654752f;
#pragma unroll
        for (int q = 0; q < QC; q++) {
            GT[q*129 + t] = g[q];
            float gs = g[q] * is2;                 // store G/sqrt(2)
            short hi = f2bf(gs);
            float hf = bf2f(hi);
            btH[(k*QC + q)*DC + t] = hi;
            btL[(k*QC + q)*DC + t] = f2bf(gs - hf);
        }
    }
    __syncthreads();
    if (t < QC) {       // h = G mu
        float s = 0.f;
        for (int d = 0; d < DC; d++)
            s = fmaf(GT[t*129 + d], muS[d], s);
        hS[t] = s;
        float hh = s*s;
        hh += __shfl_xor(hh, 1, 16);
        hh += __shfl_xor(hh, 2, 16);
        hh += __shfl_xor(hh, 4, 16);
        hh += __shfl_xor(hh, 8, 16);
        if (t == 0) hhS = hh;
    }
    {
        float a = lp, b2 = ipm;
#pragma unroll
        for (int off = 1; off < 64; off <<= 1) {
            a  += __shfl_xor(a, off, 64);
            b2 += __shfl_xor(b2, off, 64);
        }
        if (t == 0)  { redS[0] = a; redS[1] = b2; }
        if (t == 64) { redS[2] = a; redS[3] = b2; }
    }
    __syncthreads();
    if (t < DC) {       // w' = invpsi*mu - G^T h
        float gh = 0.f;
#pragma unroll
        for (int q = 0; q < QC; q++) gh = fmaf(g[q], hS[q], gh);
        float wp = invpsiS[t]*muS[t] - gh;
        short hi = f2bf(wp);
        float hf = bf2f(hi);
        btH[(512 + k)*DC + t] = hi;
        btL[(512 + k)*DC + t] = f2bf(wp - hf);
    }
    if (t == 0) {
        const float log2pi = 1.8378770664093453f;
        float slp = redS[0] + redS[2];
        float tv  = redS[1] + redS[3];
        c2p[k] = log_pi[k]
            - 0.5f*((float)DC*log2pi + slp + ldS + tv) + 0.5f*hhS;
    }
}

// ---------------------------------------------------------------------------
// Kernel 2: 32x32x16 MFMA GEMM. Grid 1280: xcd = wg&7 owns rows
// [xcd*2560, +2560) (L2-resident slab); j = wg>>3: xb = xcd*20 + j%20,
// yb = j/20 (comp group of 4). Block = 4 waves x 32 rows = 128 rows.
// LDS: 68 B-rows (64 G + 4 w') x 256B x hi/lo planes = 34816 B,
// swizzle chunk c -> c ^ (row&15). Col-tiles: ct0 = B rows 0..31,
// ct1 = 32..63, ct2 = 36..67 (cols 28..31 are the 4 w' rows; cols 0..27
// duplicate G products, never extracted -> no OOB reads).
// lr = C2' + w'.x - 0.5 s2 + ||(G/sqrt2) x||^2  (0.5s2 precomputed).
// ---------------------------------------------------------------------------
#define LHB 17408    // 68*256 bytes per plane

__global__ __launch_bounds__(256, 4) void mfa_gemm(
    const short* __restrict__ xH, const short* __restrict__ xL,
    const float* __restrict__ s2g, const float* __restrict__ c2p,
    const short* __restrict__ btH, const short* __restrict__ btL,
    float* __restrict__ out)
{
    __shared__ __align__(16) char lds[2*LHB];     // 34816 B
    int t = threadIdx.x;
    int j  = blockIdx.x >> 3;
    int xb = (blockIdx.x & 7)*20 + (j % 20);      // 0..159
    int yb = j / 20;                              // 0..7
    int w = t >> 6, l = t & 63;

    // ---- stage B panel: all loads issued before writes, swizzled ds_write
    bf16x8 rh[5], rl[5];
#pragma unroll
    for (int i = 0; i < 5; i++) {
        int s = t + i*256;                        // chunk id, 1088 total
        if (s < 1088) {
            int row = s >> 4, c = s & 15;
            int gr = (row < 64) ? (yb*64 + row) : (512 + yb*4 + (row - 64));
            rh[i] = *(const bf16x8*)(btH + gr*DC + c*8);
            rl[i] = *(const bf16x8*)(btL + gr*DC + c*8);
        }
    }

    int m32 = l & 31, kh = l >> 5;
    int rowbase = xb*128 + w*32;
    int xrow = min(rowbase + m32, NPTS - 1);
    const short* ap = xH + (size_t)xrow*DC + kh*8;
    const short* lp = xL + (size_t)xrow*DC + kh*8;

#pragma unroll
    for (int i = 0; i < 5; i++) {
        int s = t + i*256;
        if (s < 1088) {
            int row = s >> 4, c = s & 15;
            unsigned bo = (unsigned)row*256u + ((unsigned)(c ^ (row & 15)) << 4);
            *(bf16x8*)(lds + bo)       = rh[i];
            *(bf16x8*)(lds + LHB + bo) = rl[i];
        }
    }

    // b-frag row bases (per-lane), swizzle masks
    int r0 = m32, r1 = 32 + m32, r2 = 36 + m32;
    unsigned b0 = (unsigned)r0*256u, sm0 = (unsigned)(r0 & 15);
    unsigned b1 = (unsigned)r1*256u, sm1 = (unsigned)(r1 & 15);
    unsigned b2 = (unsigned)r2*256u, sm2 = (unsigned)(r2 & 15);

    // preload A kstep 0
    bf16x8 ah = *(const bf16x8*)ap;
    bf16x8 al = *(const bf16x8*)lp;

    __syncthreads();

    f32x16 acc0 = {}, acc1 = {}, acc2 = {};
#pragma unroll 1
    for (int ks = 0; ks < 8; ks++) {
        // prefetch next A (wraps harmlessly on last iter)
        int kn = (ks + 1) & 7;
        bf16x8 ahn = *(const bf16x8*)(ap + kn*16);
        bf16x8 aln = *(const bf16x8*)(lp + kn*16);

        unsigned c = (unsigned)(ks*2 + kh);
        unsigned o0 = b0 + ((c ^ sm0) << 4);
        unsigned o1 = b1 + ((c ^ sm1) << 4);
        unsigned o2 = b2 + ((c ^ sm2) << 4);
        bf16x8 bh0 = *(const bf16x8*)(lds + o0);
        bf16x8 bl0 = *(const bf16x8*)(lds + LHB + o0);
        bf16x8 bh1 = *(const bf16x8*)(lds + o1);
        bf16x8 bl1 = *(const bf16x8*)(lds + LHB + o1);
        bf16x8 bh2 = *(const bf16x8*)(lds + o2);
        bf16x8 bl2 = *(const bf16x8*)(lds + LHB + o2);

        acc0 = __builtin_amdgcn_mfma_f32_32x32x16_bf16(ah, bh0, acc0, 0, 0, 0);
        acc1 = __builtin_amdgcn_mfma_f32_32x32x16_bf16(ah, bh1, acc1, 0, 0, 0);
        acc2 = __builtin_amdgcn_mfma_f32_32x32x16_bf16(ah, bh2, acc2, 0, 0, 0);
        acc0 = __builtin_amdgcn_mfma_f32_32x32x16_bf16(al, bh0, acc0, 0, 0, 0);
        acc1 = __builtin_amdgcn_mfma_f32_32x32x16_bf16(al, bh1, acc1, 0, 0, 0);
        acc2 = __builtin_amdgcn_mfma_f32_32x32x16_bf16(al, bh2, acc2, 0, 0, 0);
        acc0 = __builtin_amdgcn_mfma_f32_32x32x16_bf16(ah, bl0, acc0, 0, 0, 0);
        acc1 = __builtin_amdgcn_mfma_f32_32x32x16_bf16(ah, bl1, acc1, 0, 0, 0);
        acc2 = __builtin_amdgcn_mfma_f32_32x32x16_bf16(ah, bl2, acc2, 0, 0, 0);

        ah = ahn; al = aln;
    }

    // ---- epilogue ----
    // C/D layout: col = lane&31, row = (reg&3) + 8*(reg>>2) + 4*(lane>>5)
    int cc = (m32 - 28) & 3;
    float c2v = c2p[yb*4 + cc];
    bool writer = (m32 >= 28);
#pragma unroll
    for (int r = 0; r < 16; r++) {
        float v0 = acc0[r]*acc0[r];
        v0 += __shfl_xor(v0, 1, 64);
        v0 += __shfl_xor(v0, 2, 64);
        v0 += __shfl_xor(v0, 4, 64);
        v0 += __shfl_xor(v0, 8, 64);
        float u0 = __shfl_xor(v0, 16, 64);
        float v1 = acc1[r]*acc1[r];
        v1 += __shfl_xor(v1, 1, 64);
        v1 += __shfl_xor(v1, 2, 64);
        v1 += __shfl_xor(v1, 4, 64);
        v1 += __shfl_xor(v1, 8, 64);
        float u1 = __shfl_xor(v1, 16, 64);
        if (writer) {
            // writer lane m32 = 28+cc is in col-group 16..31:
            // v = own-group sum (cols 16-31), u = other group (cols 0-15)
            float q = (cc == 0) ? u0 : (cc == 1) ? v0 : (cc == 2) ? u1 : v1;
            int grow = rowbase + (r & 3) + 8*(r >> 2) + 4*kh;
            if (grow < NPTS) {
                float lr = c2v + acc2[r] - s2g[grow] + q;
                out[(size_t)grow*KC + yb*4 + cc] = lr;
            }
        }
    }
}

// ---------------------------------------------------------------------------
// Kernel 3: in-place logsumexp normalize + log-likelihood output.
// ---------------------------------------------------------------------------
__global__ __launch_bounds__(256) void mfa_norm(float* __restrict__ out)
{
    int n = blockIdx.x * 256 + threadIdx.x;
    if (n >= NPTS) return;
    float lr[KC];
#pragma unroll
    for (int i = 0; i < 8; i++)
        *(float4*)&lr[i*4] = *(const float4*)(out + (size_t)n*KC + i*4);
    float m = -1e30f;
#pragma unroll
    for (int k = 0; k < KC; k++) m = fmaxf(m, lr[k]);
    float s = 0.0f;
#pragma unroll
    for (int k = 0; k < KC; k++) s += expf(lr[k] - m);
    float ll = m + logf(s);
#pragma unroll
    for (int k = 0; k < KC; k++) lr[k] -= ll;
#pragma unroll
    for (int i = 0; i < 8; i++)
        *(float4*)(out + (size_t)n*KC + i*4) = *(const float4*)&lr[i*4];
    out[(size_t)NPTS*KC + n] = ll;
}

extern "C" void kernel_launch(void* const* d_in, const int* in_sizes, int n_in,
                              void* d_out, int out_size, void* d_ws, size_t ws_size,
                              hipStream_t stream)
{
    const float* X       = (const float*)d_in[0];
    const float* log_pi  = (const float*)d_in[1];
    const float* mu      = (const float*)d_in[2];
    const float* Lam     = (const float*)d_in[3];
    const float* log_psi = (const float*)d_in[4];
    float* out = (float*)d_out;
    char* wsb = (char*)d_ws;
    float* c2p = (float*)(wsb + WS_C2P_B);
    short* btH = (short*)(wsb + WS_BTH_B);
    short* btL = (short*)(wsb + WS_BTL_B);
    short* xH  = (short*)(wsb + WS_XH_B);
    short* xL  = (short*)(wsb + WS_XL_B);
    float* s2g = (float*)(wsb + WS_S2_B);

    hipLaunchKernelGGL(mfa_prep, dim3(KC + 314), dim3(256), 0, stream,
                       X, log_pi, mu, Lam, log_psi, c2p, btH, btL, xH, xL, s2g);
    hipLaunchKernelGGL(mfa_gemm, dim3(1280), dim3(256), 0, stream,
                       xH, xL, s2g, c2p, btH, btL, out);
    hipLaunchKernelGGL(mfa_norm, dim3(79), dim3(256), 0, stream, out);
}